// Round 10
// baseline (692.078 us; speedup 1.0000x reference)
//
#include <hip/hip_runtime.h>

typedef unsigned short u16;
typedef short bf16x8 __attribute__((ext_vector_type(8)));
typedef u16 u16x8 __attribute__((ext_vector_type(8)));
typedef float f32x4 __attribute__((ext_vector_type(4)));

__device__ __forceinline__ float bf2f(u16 u) {
    union { unsigned u; float f; } c; c.u = ((unsigned)u) << 16; return c.f;
}
__device__ __forceinline__ u16 f2bf(float f) {
    union { float f; unsigned u; } c; c.f = f;
    unsigned r = c.u + 0x7FFFu + ((c.u >> 16) & 1u);
    return (u16)(r >> 16);
}
__device__ __forceinline__ float tanh_fast(float x) {
    float e = __expf(2.0f * x);
    return 1.0f - 2.0f / (e + 1.0f);
}
__device__ __forceinline__ void gll16(const void* g, void* l) {
    __builtin_amdgcn_global_load_lds((const __attribute__((address_space(1))) void*)g,
                                     (__attribute__((address_space(3))) void*)l, 16, 0, 0);
}

#define BAR() __builtin_amdgcn_s_barrier()

// ---------------- f32 -> bf16 convert, 8 elems/thread ----------------
__global__ __launch_bounds__(256) void cvt_f32_bf16(const float* __restrict__ src,
                                                    u16* __restrict__ dst, int n8) {
    int i = blockIdx.x * blockDim.x + threadIdx.x;
    int stride = gridDim.x * blockDim.x;
    for (; i < n8; i += stride) {
        const float4* s = (const float4*)(src + (size_t)i * 8);
        float4 a = s[0], b = s[1];
        u16x8 o;
        o[0] = f2bf(a.x); o[1] = f2bf(a.y); o[2] = f2bf(a.z); o[3] = f2bf(a.w);
        o[4] = f2bf(b.x); o[5] = f2bf(b.y); o[6] = f2bf(b.z); o[7] = f2bf(b.w);
        *(u16x8*)(dst + (size_t)i * 8) = o;
    }
}

// ---------------- mq = tanh(Wm @ m_q + bm), one wave per output ----------------
__global__ __launch_bounds__(256) void mq_kernel(const float* __restrict__ Wm,
                                                 const float* __restrict__ q,
                                                 const float* __restrict__ bm,
                                                 float* __restrict__ mq, int D) {
    int w = threadIdx.x >> 6, l = threadIdx.x & 63;
    int e = blockIdx.x * 4 + w;
    const float* wp = Wm + (size_t)e * D;
    float s = 0.f;
    for (int j = 0; j < D; j += 256) {
        float4 wv = *(const float4*)(wp + j + l * 4);
        float4 qv = *(const float4*)(q + j + l * 4);
        s += wv.x * qv.x + wv.y * qv.y + wv.z * qv.z + wv.w * qv.w;
    }
    #pragma unroll
    for (int o = 32; o >= 1; o >>= 1) s += __shfl_xor(s, o);
    if (l == 0) mq[e] = tanh_fast(s + bm[e]);
}

// ---- C[M,N] = A[M,K] @ B[N,K]^T : 256x256, BK=32, 4 slots, ONE barrier per K-tile ----
// 8 waves (2M x 4N; per-wave 128x64). LDS 128 KiB = {A,B} x 4 K-tile slots x 16 KiB.
// Slot layout (pair-interleaved, conflict-free): [128 pair-lines][128B]; line p holds
// rows {2p, 2p+1}; phys 16B-slot = ((r&1)*4 + ks) ^ (p&7), ks = 16B k-slot (0..3).
// Iter t: read slot t&3 (12 ds_read_b128) ; stage slot (t+2)&3 (4 gll16, issue-early) ;
// 32 MFMA (lgkm-gated by compiler) ; vmcnt(4) seals slot t+1 ; s_barrier.
// Race-safety: write slot (t+2)&3 vs its last reads (iter t-2) = 2 barriers apart;
// reads of slot t sealed by vmcnt(4)+barrier at end of iter t-1.
// EPI=0: C = bf16( tanh(acc+bias[col]) * gate[col] );  EPI=1: C = bf16(acc+bias[col])
template <int EPI>
__global__ __launch_bounds__(512, 2) void gemm_1b(const u16* __restrict__ A,
                                                  const u16* __restrict__ B,
                                                  const float* __restrict__ bias,
                                                  const float* __restrict__ gate,
                                                  u16* __restrict__ C,
                                                  int M, int N, int K) {
    __shared__ u16 sh[65536];            // 128 KiB: A slots 0..3 @0, B slots 0..3 @65536
    char* LDS = (char*)sh;
    const int K2 = K * 2;
    const int KT = K >> 5;               // K-tiles of 32 (64 here, multiple of 4)

    const int tid = threadIdx.x;
    const int w = tid >> 6, l = tid & 63;
    const int wm = w >> 2, wn = w & 3;

    // XCD-aware swizzle (nwg = 1024, divisible by 8)
    int orig = blockIdx.x + gridDim.x * blockIdx.y;
    int nwg = gridDim.x * gridDim.y;
    int id = ((nwg & 7) == 0) ? ((orig & 7) * (nwg >> 3) + (orig >> 3)) : orig;
    const int tileN = (id % gridDim.x) * 256;
    const int tileM = (id / gridDim.x) * 256;

    // ---- staging geometry: wave w, call j covers chunk = w*2+j (16 rows = 8 pair-lines).
    // lane l: p = l>>3 (pair in chunk), q = l&7 (phys slot); e = q^p (logical) ->
    // row-in-chunk = 2p + (e>>2), col byte = (e&3)*16. Dest: uniform base + HW lane*16.
    const int e_sw = (l & 7) ^ (l >> 3);
    const int r_lane = 2 * (l >> 3) + (e_sw >> 2);
    const int c_lane = (e_sw & 3) << 4;
    const int ch0 = w * 2, ch1 = w * 2 + 1;
    const char* sA0 = (const char*)A + (size_t)(tileM + ch0 * 16 + r_lane) * K2 + c_lane;
    const char* sA1 = (const char*)A + (size_t)(tileM + ch1 * 16 + r_lane) * K2 + c_lane;
    const char* sB0 = (const char*)B + (size_t)(tileN + ch0 * 16 + r_lane) * K2 + c_lane;
    const char* sB1 = (const char*)B + (size_t)(tileN + ch1 * 16 + r_lane) * K2 + c_lane;
    char* dA0 = LDS + ch0 * 1024;
    char* dA1 = LDS + ch1 * 1024;
    char* dB0 = LDS + 65536 + ch0 * 1024;
    char* dB1 = LDS + 65536 + ch1 * 1024;

#define STG(tk, SB) do { size_t go = (size_t)(tk) * 64;                         \
    gll16(sA0 + go, dA0 + (SB)); gll16(sA1 + go, dA1 + (SB));                   \
    gll16(sB0 + go, dB0 + (SB)); gll16(sB1 + go, dB1 + (SB)); } while (0)

    // ---- reader: frag row r = rowbase + (l&15), ks = l>>4. rowbase % 16 == 0 =>
    // (r>>1)&7 = (l&15)>>1. byte = rowbase*64 + prd, prd lane-constant:
    const int prd = ((l & 15) >> 1) * 128 +
                    ((((l & 1) << 2) | (l >> 4)) ^ ((l & 15) >> 1)) * 16;
    const char* pRA = LDS + wm * 8192 + prd;            // + slot*16384 + fm*1024
    const char* pRB = LDS + 65536 + wn * 4096 + prd;    // + slot*16384 + fn*1024

    f32x4 acc[8][4] = {};

    // ---- prologue: stage tiles 0,1 into slots 0,1; seal slot 0 ----
    STG(0, 0); STG(1, 16384);
    asm volatile("s_waitcnt vmcnt(4)" ::: "memory");
    BAR();

#define ITER(t, P) do {                                                         \
    constexpr int SL = (P) * 16384;                                             \
    constexpr int SN = (((P) + 2) & 3) * 16384;                                 \
    bf16x8 af[8], bf[4];                                                        \
    _Pragma("unroll")                                                           \
    for (int fm = 0; fm < 8; ++fm)                                              \
        af[fm] = *(const bf16x8*)(pRA + SL + fm * 1024);                        \
    _Pragma("unroll")                                                           \
    for (int fn = 0; fn < 4; ++fn)                                              \
        bf[fn] = *(const bf16x8*)(pRB + SL + fn * 1024);                        \
    if ((t) + 2 < KT) STG((t) + 2, SN);                                         \
    __builtin_amdgcn_s_setprio(1);                                              \
    _Pragma("unroll")                                                           \
    for (int fm = 0; fm < 8; ++fm)                                              \
        _Pragma("unroll")                                                       \
        for (int fn = 0; fn < 4; ++fn)                                          \
            acc[fm][fn] = __builtin_amdgcn_mfma_f32_16x16x32_bf16(              \
                af[fm], bf[fn], acc[fm][fn], 0, 0, 0);                          \
    __builtin_amdgcn_s_setprio(0);                                              \
    if ((t) + 2 < KT) asm volatile("s_waitcnt vmcnt(4)" ::: "memory");          \
    else              asm volatile("s_waitcnt vmcnt(0)" ::: "memory");          \
    BAR();                                                                      \
} while (0)

    for (int tt = 0; tt < KT; tt += 4) {
        ITER(tt, 0);
        ITER(tt + 1, 1);
        ITER(tt + 2, 2);
        ITER(tt + 3, 3);
    }
#undef ITER
#undef STG

    // ---- epilogue: C/D layout col = lane&15, row = (lane>>4)*4 + reg ----
    const int cr = (l >> 4) * 4;
    const int cl = l & 15;
    #pragma unroll
    for (int fn = 0; fn < 4; ++fn) {
        const int col = tileN + wn * 64 + fn * 16 + cl;
        const float bs = bias[col];
        float gt = 0.f;
        if (EPI == 0) gt = gate[col];
        #pragma unroll
        for (int fm = 0; fm < 8; ++fm)
            #pragma unroll
            for (int r = 0; r < 4; ++r) {
                const int row = tileM + wm * 128 + fm * 16 + cr + r;
                float v = acc[fm][fn][r] + bs;
                if (EPI == 0) v = tanh_fast(v) * gt;
                C[(size_t)row * N + col] = f2bf(v);
            }
    }
}

// ---------------- row softmax + weighted sum + m_q_new ----------------
__global__ __launch_bounds__(256) void softmax_out(const u16* __restrict__ logits,
                                                   const float* __restrict__ hidden,
                                                   const float* __restrict__ m_q,
                                                   float* __restrict__ out,
                                                   int D, int R) {
    const int r = blockIdx.x;
    const int t = threadIdx.x;
    const int w = t >> 6, l = t & 63;
    const u16* lp = logits + (size_t)r * D + t * 8;
    const float* hp = hidden + (size_t)r * D + t * 8;

    bf16x8 lv = *(const bf16x8*)lp;
    float lf[8];
    #pragma unroll
    for (int j = 0; j < 8; ++j) lf[j] = bf2f((u16)lv[j]);
    float4 h0 = *(const float4*)hp;
    float4 h1 = *(const float4*)(hp + 4);
    float hv[8] = {h0.x, h0.y, h0.z, h0.w, h1.x, h1.y, h1.z, h1.w};

    float m = lf[0];
    #pragma unroll
    for (int j = 1; j < 8; ++j) m = fmaxf(m, lf[j]);
    #pragma unroll
    for (int o = 32; o >= 1; o >>= 1) m = fmaxf(m, __shfl_xor(m, o));

    __shared__ float red[8];
    if (l == 0) red[w] = m;
    __syncthreads();
    m = fmaxf(fmaxf(red[0], red[1]), fmaxf(red[2], red[3]));
    __syncthreads();

    float se = 0.f, sh = 0.f;
    #pragma unroll
    for (int j = 0; j < 8; ++j) {
        float e = __expf(lf[j] - m);
        se += e;
        sh += e * hv[j];
    }
    #pragma unroll
    for (int o = 32; o >= 1; o >>= 1) { se += __shfl_xor(se, o); sh += __shfl_xor(sh, o); }
    if (l == 0) { red[w] = se; red[4 + w] = sh; }
    __syncthreads();
    if (t == 0) {
        float SE = red[0] + red[1] + red[2] + red[3];
        float SH = red[4] + red[5] + red[6] + red[7];
        float o = SH / SE;
        out[r] = o;
        out[R + r] = m_q[r & (D - 1)] + o;
    }
}

extern "C" void kernel_launch(void* const* d_in, const int* in_sizes, int n_in,
                              void* d_out, int out_size, void* d_ws, size_t ws_size,
                              hipStream_t stream) {
    const float* hidden = (const float*)d_in[0];
    const float* m_q    = (const float*)d_in[1];
    const float* Wq     = (const float*)d_in[2];
    const float* bq     = (const float*)d_in[3];
    const float* Wm     = (const float*)d_in[4];
    const float* bm     = (const float*)d_in[5];
    const float* Wa     = (const float*)d_in[6];
    const float* ba     = (const float*)d_in[7];
    float* out = (float*)d_out;

    const int D = 2048;
    const int M = 16 * 2048;  // B*S = 32768

    char* ws = (char*)d_ws;
    size_t oH  = 0;
    size_t oS  = oH  + (size_t)M * D * 2;   // Sg bf16
    size_t oWq = oS  + (size_t)M * D * 2;
    size_t oWa = oWq + (size_t)D * D * 2;
    size_t oMq = oWa + (size_t)D * D * 2;
    size_t need = oMq + (size_t)D * sizeof(float);
    if (ws_size < need) return;

    u16* hbf    = (u16*)(ws + oH);
    u16* Sg     = (u16*)(ws + oS);
    u16* Wqb    = (u16*)(ws + oWq);
    u16* Wab    = (u16*)(ws + oWa);
    float* mq   = (float*)(ws + oMq);
    u16* logits = hbf;  // alias: hidden_bf16 dead after GEMM1

    cvt_f32_bf16<<<4096, 256, 0, stream>>>(hidden, hbf, M * D / 8);
    cvt_f32_bf16<<<1024, 256, 0, stream>>>(Wq, Wqb, D * D / 8);
    cvt_f32_bf16<<<1024, 256, 0, stream>>>(Wa, Wab, D * D / 8);
    mq_kernel<<<D / 4, 256, 0, stream>>>(Wm, m_q, bm, mq, D);

    dim3 grid(D / 256, M / 256);  // (8, 128)
    gemm_1b<0><<<grid, 512, 0, stream>>>(hbf, Wqb, bq, mq, Sg, M, D, D);
    gemm_1b<1><<<grid, 512, 0, stream>>>(Sg, Wab, ba, nullptr, logits, M, D, D);

    softmax_out<<<M, 256, 0, stream>>>(logits, hidden, m_q, out, D, M);
}